// Round 1
// baseline (288.795 us; speedup 1.0000x reference)
//
#include <hip/hip_runtime.h>
#include <hip/hip_bf16.h>

#define TOKENS 2048
#define DIM 512
#define NEXP 16
#define HID 2048
#define CAP 320                 /* rows per expert (mean 256, +4 sigma margin) */
#define NTPE (CAP / 64)         /* 5 m-tiles per expert */
#define MTILES (NEXP * NTPE)    /* 80 */
#define NROWS (NEXP * CAP)      /* 5120 */

typedef unsigned short ushort_t;
typedef __attribute__((ext_vector_type(8))) __bf16 bf16x8;
typedef __attribute__((ext_vector_type(4))) float f32x4;

// workspace byte offsets (total 90,260,480 <= known-good 90.3MB)
#define OFF_CNT 0
#define OFF_LTOK 1024
#define OFF_LW 21504
#define OFF_S1 41984
#define OFF_S2 62464
#define OFF_XBF 82944        /* 2048*512*2 = 2,097,152 -> ends 2,180,096 */
#define OFF_H 2180096        /* 5120*2048*2 = 20,971,520 -> ends 23,151,616 */
#define OFF_W1T 23151616     /* 33,554,432 -> ends 56,706,048 */
#define OFF_W2T 56706048     /* 33,554,432 -> ends 90,260,480 */

__device__ __forceinline__ ushort_t f2b(float f) {
  __bf16 b = (__bf16)f;
  return __builtin_bit_cast(unsigned short, b);
}
__device__ __forceinline__ float b2f(ushort_t u) {
  return __builtin_bit_cast(float, (unsigned)u << 16);
}

// ---------- weight convert+transpose (both W1 and W2 in one launch) ---------
// src[E][K][N] f32 -> dst[E][N][K] bf16
// 4 sub-tiles (32x32) per block along n, double-buffered LDS, 1 sync/sub-tile
__global__ __launch_bounds__(256) void wconv_k(
    const float* __restrict__ W1, const float* __restrict__ W2,
    ushort_t* __restrict__ W1t, ushort_t* __restrict__ W2t,
    int* __restrict__ counts) {
  if (blockIdx.x == 0 && blockIdx.y == 0 && threadIdx.x < NEXP)
    counts[threadIdx.x] = 0;
  int bx = blockIdx.x;
  const float* src;
  ushort_t* dst;
  int K, N, nnc;
  if (bx < 256) { src = W1; dst = W1t; K = DIM; N = HID; nnc = 16; }
  else { src = W2; dst = W2t; K = HID; N = DIM; nnc = 4; bx -= 256; }
  int e = blockIdx.y;
  int kt = bx / nnc, nb = bx % nnc;
  int k0 = kt * 32, n0 = nb * 128;
  __shared__ ushort_t Ls[2][32 * 33];
  int t = threadIdx.x;
  int r = t >> 3, c4 = (t & 7) * 4;
  const float* sp = src + ((size_t)e * K + k0 + r) * N + n0 + c4;
  ushort_t* dp = dst + ((size_t)e * N + n0 + r) * K + k0 + c4;
  float4 v = *(const float4*)sp;
#pragma unroll
  for (int j = 0; j < 4; j++) {
    ushort_t* L = Ls[j & 1];
    L[r * 33 + c4 + 0] = f2b(v.x);
    L[r * 33 + c4 + 1] = f2b(v.y);
    L[r * 33 + c4 + 2] = f2b(v.z);
    L[r * 33 + c4 + 3] = f2b(v.w);
    float4 vn;
    if (j < 3) vn = *(const float4*)(sp + (j + 1) * 32);
    __syncthreads();
    union { ushort_t u[4]; unsigned long long q; } o;
#pragma unroll
    for (int i = 0; i < 4; i++) o.u[i] = L[(c4 + i) * 33 + r];
    *(unsigned long long*)(dp + (size_t)(j * 32) * K) = o.q;
    v = vn;
  }
}

// ---------------- router: logits, top-2, softmax, slot assignment -----------
__global__ __launch_bounds__(256) void router_k(
    const float* __restrict__ x, const float* __restrict__ Wg,
    ushort_t* __restrict__ xbf, int* __restrict__ counts,
    int* __restrict__ ltok, float* __restrict__ lw,
    float* __restrict__ s1, float* __restrict__ s2, float* __restrict__ out) {
  int t = threadIdx.x;
  {
    float4 z = {0.f, 0.f, 0.f, 0.f};
    float4* o4 = (float4*)out + blockIdx.x * 4096 + t;
#pragma unroll
    for (int i = 0; i < 16; i++) o4[i * 256] = z;
  }
  {
    int idx = blockIdx.x * 256 + t;
    if (idx < NROWS) { s1[idx] = 0.f; s2[idx] = 0.f; }
  }

  __shared__ float xs[4][512];
  __shared__ float lg[4][16];
  __shared__ int lcnt[NEXP];
  __shared__ int ltoks[NEXP][64];
  __shared__ float lws[NEXP][64];
  __shared__ int base_s[NEXP];

  if (t < NEXP) lcnt[t] = 0;
  __syncthreads();

  int lane = t & 63, w = t >> 6;
  int dq = lane >> 2, e4 = lane & 3;
  const float* wgp = Wg + dq * NEXP + e4 * 4;

  for (int it = 0; it < 8; it++) {
    int tok = blockIdx.x * 32 + w * 8 + it;
    const float* xr = x + (size_t)tok * DIM + lane * 8;
    float4 xa = *(const float4*)xr;
    float4 xb = *(const float4*)(xr + 4);
    union { ushort_t u[8]; uint4 v; } pk;
    pk.u[0] = f2b(xa.x); pk.u[1] = f2b(xa.y); pk.u[2] = f2b(xa.z); pk.u[3] = f2b(xa.w);
    pk.u[4] = f2b(xb.x); pk.u[5] = f2b(xb.y); pk.u[6] = f2b(xb.z); pk.u[7] = f2b(xb.w);
    *(uint4*)(xbf + (size_t)tok * DIM + lane * 8) = pk.v;
    *(float4*)&xs[w][lane * 8] = xa;
    *(float4*)&xs[w][lane * 8 + 4] = xb;

    float4 a = {0.f, 0.f, 0.f, 0.f};
#pragma unroll
    for (int kk = 0; kk < 32; kk++) {
      float xv = xs[w][kk * 16 + dq];
      float4 g = *(const float4*)(wgp + kk * 16 * NEXP);
      a.x += xv * g.x; a.y += xv * g.y; a.z += xv * g.z; a.w += xv * g.w;
    }
#pragma unroll
    for (int off = 32; off >= 4; off >>= 1) {
      a.x += __shfl_down(a.x, off);
      a.y += __shfl_down(a.y, off);
      a.z += __shfl_down(a.z, off);
      a.w += __shfl_down(a.w, off);
    }
    if (lane < 4) *(float4*)&lg[w][lane * 4] = a;
    if (lane == 0) {
      int i0 = 0;
      float v0 = lg[w][0];
#pragma unroll
      for (int e = 1; e < NEXP; e++)
        if (lg[w][e] > v0) { v0 = lg[w][e]; i0 = e; }
      int i1 = -1;
      float v1 = -3.4e38f;
#pragma unroll
      for (int e = 0; e < NEXP; e++)
        if (e != i0 && lg[w][e] > v1) { v1 = lg[w][e]; i1 = e; }
      float ex = __expf(v1 - v0);
      float w0 = 1.f / (1.f + ex);
      int p0 = atomicAdd(&lcnt[i0], 1);
      ltoks[i0][p0] = tok;
      lws[i0][p0] = w0;
      int p1 = atomicAdd(&lcnt[i1], 1);
      ltoks[i1][p1] = tok;
      lws[i1][p1] = ex / (1.f + ex);
    }
  }
  __syncthreads();
  if (t < NEXP) base_s[t] = atomicAdd(&counts[t], lcnt[t]);
  __syncthreads();
  int e = t >> 4, i0 = t & 15;
  int n = lcnt[e], b = base_s[e];
  for (int i = i0; i < n; i += 16) {
    int slot = b + i;
    if (slot < CAP) {
      ltok[e * CAP + slot] = ltoks[e][i];
      lw[e * CAP + slot] = lws[e][i];
    }
  }
}

// ---------------- GEMM1: h = silu(x @ W1 + b1), store bf16 + row stats ------
// W1t: [E][H][D] bf16 (k=D contiguous). M=64, N=256/block.
// Double-buffered LDS, 1 barrier/K-step, loads pipelined 1-2 steps ahead.
__global__ __launch_bounds__(256) void ffn1_k(
    const ushort_t* __restrict__ W1t, const float* __restrict__ b1,
    const int* __restrict__ counts, const int* __restrict__ ltok,
    const ushort_t* __restrict__ xbf, ushort_t* __restrict__ hbuf,
    float* __restrict__ s1, float* __restrict__ s2) {
  int e = blockIdx.x / NTPE, mt = blockIdx.x % NTPE;
  int cnt = counts[e];
  if (cnt - mt * 64 <= 0) return;
  int row0 = e * CAP + mt * 64;
  int h0 = blockIdx.y * 256;

  __shared__ __align__(16) ushort_t As[2][64 * 40];

  int t = threadIdx.x;
  int lane = t & 63, wave = t >> 6;
  int quad = lane >> 4, l16 = lane & 15;

  int sr = t >> 2, sp = t & 3;
  int stok = ltok[row0 + sr];
  bool sok = (unsigned)stok < TOKENS;
  const ushort_t* sx = xbf + (size_t)(sok ? stok : 0) * DIM + sp * 8;

  int ncol = h0 + wave * 64 + l16;
  const ushort_t* bb = W1t + ((size_t)e * HID + ncol) * DIM + quad * 8;

  f32x4 acc[4][4];
#pragma unroll
  for (int a = 0; a < 4; a++)
#pragma unroll
    for (int b = 0; b < 4; b++) acc[a][b] = {0.f, 0.f, 0.f, 0.f};

  // prologue: A(0) -> LDS[0], A(1) in regs, B(0) in regs
  uint4 avB = {0u, 0u, 0u, 0u};
  {
    uint4 avA = {0u, 0u, 0u, 0u};
    if (sok) {
      avA = *(const uint4*)(sx);
      avB = *(const uint4*)(sx + 32);
    }
    *(uint4*)(&As[0][sr * 40 + sp * 8]) = avA;
  }
  bf16x8 bc[4];
#pragma unroll
  for (int nb = 0; nb < 4; nb++)
    bc[nb] = *(const bf16x8*)(bb + (size_t)nb * 16 * DIM);

#pragma unroll
  for (int ks = 0; ks < 16; ks++) {
    __syncthreads();  // LDS[ks&1] ready
    // issue next loads right after the barrier: full-iteration cover
    bf16x8 bn[4];
    if (ks < 15) {
#pragma unroll
      for (int nb = 0; nb < 4; nb++)
        bn[nb] = *(const bf16x8*)(bb + (size_t)nb * 16 * DIM + (ks + 1) * 32);
    }
    uint4 avN = {0u, 0u, 0u, 0u};
    if (ks < 14 && sok) avN = *(const uint4*)(sx + (ks + 2) * 32);

    bf16x8 af[4];
#pragma unroll
    for (int mb = 0; mb < 4; mb++)
      af[mb] = *(const bf16x8*)(&As[ks & 1][(mb * 16 + l16) * 40 + quad * 8]);
#pragma unroll
    for (int mb = 0; mb < 4; mb++)
#pragma unroll
      for (int nb = 0; nb < 4; nb++)
        acc[mb][nb] = __builtin_amdgcn_mfma_f32_16x16x32_bf16(af[mb], bc[nb], acc[mb][nb], 0, 0, 0);

    if (ks < 15) {
      *(uint4*)(&As[(ks + 1) & 1][sr * 40 + sp * 8]) = avB;
      avB = avN;
#pragma unroll
      for (int nb = 0; nb < 4; nb++) bc[nb] = bn[nb];
    }
  }

  float bia[4];
#pragma unroll
  for (int nb = 0; nb < 4; nb++) bia[nb] = b1[e * HID + ncol + nb * 16];
#pragma unroll
  for (int mb = 0; mb < 4; mb++) {
#pragma unroll
    for (int i = 0; i < 4; i++) {
      int m = mb * 16 + quad * 4 + i;
      size_t rowg = (size_t)(row0 + m);
      float ps = 0.f, qs = 0.f;
#pragma unroll
      for (int nb = 0; nb < 4; nb++) {
        float v = acc[mb][nb][i] + bia[nb];
        v = v / (1.f + __expf(-v));
        hbuf[rowg * HID + ncol + nb * 16] = f2b(v);
        ps += v;
        qs += v * v;
      }
      ps += __shfl_down(ps, 8); qs += __shfl_down(qs, 8);
      ps += __shfl_down(ps, 4); qs += __shfl_down(qs, 4);
      ps += __shfl_down(ps, 2); qs += __shfl_down(qs, 2);
      ps += __shfl_down(ps, 1); qs += __shfl_down(qs, 1);
      if (l16 == 0) {
        atomicAdd(&s1[rowg], ps);
        atomicAdd(&s2[rowg], qs);
      }
    }
  }
}

// ---------------- GEMM2: out[t] += w * (LN(h) @ W2 + b2) --------------------
// W2t: [E][D][H] bf16 (k=H contiguous). M=64, N=256/block, K split in 2 (z).
// gamma/beta pre-staged in LDS; double-buffered pipelined K-loop.
__global__ __launch_bounds__(256) void ffn2_k(
    const ushort_t* __restrict__ W2t, const float* __restrict__ b2,
    const float* __restrict__ lng, const float* __restrict__ lnb,
    const int* __restrict__ counts, const int* __restrict__ ltok,
    const float* __restrict__ lw, const ushort_t* __restrict__ hbuf,
    const float* __restrict__ s1, const float* __restrict__ s2,
    float* __restrict__ out) {
  int e = blockIdx.x / NTPE, mt = blockIdx.x % NTPE;
  int cnt = counts[e];
  int valid = cnt - mt * 64;
  if (valid <= 0) return;
  valid = valid > 64 ? 64 : valid;
  int row0 = e * CAP + mt * 64;
  int n0 = blockIdx.y * 256;
  int kbeg = blockIdx.z * (HID / 2);

  __shared__ __align__(16) ushort_t As[2][64 * 40];
  __shared__ float Gs[1024];
  __shared__ float Cs[1024];

  int t = threadIdx.x;
  int lane = t & 63, wave = t >> 6;
  int quad = lane >> 4, l16 = lane & 15;

  // stage gamma/beta slice once
  *(float4*)&Gs[t * 4] = *(const float4*)(lng + (size_t)e * HID + kbeg + t * 4);
  *(float4*)&Cs[t * 4] = *(const float4*)(lnb + (size_t)e * HID + kbeg + t * 4);

  int sr = t >> 2, sp = t & 3;
  size_t srow = (size_t)(row0 + sr);
  const ushort_t* hr = hbuf + srow * HID + kbeg + sp * 8;
  float smu = s1[srow] * (1.f / HID);
  float var = s2[srow] * (1.f / HID) - smu * smu;
  float srs = rsqrtf(var + 1e-5f);

  int ncol = n0 + wave * 64 + l16;
  const ushort_t* bb = W2t + ((size_t)e * DIM + ncol) * HID + kbeg + quad * 8;

  f32x4 acc[4][4];
#pragma unroll
  for (int a = 0; a < 4; a++)
#pragma unroll
    for (int b = 0; b < 4; b++) acc[a][b] = {0.f, 0.f, 0.f, 0.f};

  uint4 hvA = *(const uint4*)(hr);
  uint4 hvB = *(const uint4*)(hr + 32);
  __syncthreads();  // Gs/Cs ready

  // process step0 -> LDS[0]
  {
    union { uint4 v; ushort_t u[8]; } hv;
    hv.v = hvA;
    int sb = sp * 8;
    union { ushort_t u[8]; uint4 v; } pk;
#pragma unroll
    for (int j = 0; j < 8; j++) {
      float f = (b2f(hv.u[j]) - smu) * srs;
      pk.u[j] = f2b(f * Gs[sb + j] + Cs[sb + j]);
    }
    *(uint4*)(&As[0][sr * 40 + sp * 8]) = pk.v;
  }
  bf16x8 bc[4];
#pragma unroll
  for (int nb = 0; nb < 4; nb++)
    bc[nb] = *(const bf16x8*)(bb + (size_t)nb * 16 * HID);

#pragma unroll 8
  for (int ks = 0; ks < 32; ks++) {
    __syncthreads();  // LDS[ks&1] ready
    bf16x8 bn[4];
    if (ks < 31) {
#pragma unroll
      for (int nb = 0; nb < 4; nb++)
        bn[nb] = *(const bf16x8*)(bb + (size_t)nb * 16 * HID + (ks + 1) * 32);
    }
    uint4 hvN = {0u, 0u, 0u, 0u};
    if (ks < 30) hvN = *(const uint4*)(hr + (ks + 2) * 32);

    bf16x8 af[4];
#pragma unroll
    for (int mb = 0; mb < 4; mb++)
      af[mb] = *(const bf16x8*)(&As[ks & 1][(mb * 16 + l16) * 40 + quad * 8]);
#pragma unroll
    for (int mb = 0; mb < 4; mb++)
#pragma unroll
      for (int nb = 0; nb < 4; nb++)
        acc[mb][nb] = __builtin_amdgcn_mfma_f32_16x16x32_bf16(af[mb], bc[nb], acc[mb][nb], 0, 0, 0);

    if (ks < 31) {
      union { uint4 v; ushort_t u[8]; } hv;
      hv.v = hvB;
      int sb = (ks + 1) * 32 + sp * 8;
      union { ushort_t u[8]; uint4 v; } pk;
#pragma unroll
      for (int j = 0; j < 8; j++) {
        float f = (b2f(hv.u[j]) - smu) * srs;
        pk.u[j] = f2b(f * Gs[sb + j] + Cs[sb + j]);
      }
      *(uint4*)(&As[(ks + 1) & 1][sr * 40 + sp * 8]) = pk.v;
      hvB = hvN;
#pragma unroll
      for (int nb = 0; nb < 4; nb++) bc[nb] = bn[nb];
    }
  }

  bool addb = (blockIdx.z == 0);
  float bia[4];
#pragma unroll
  for (int nb = 0; nb < 4; nb++)
    bia[nb] = addb ? b2[e * DIM + ncol + nb * 16] : 0.f;
#pragma unroll
  for (int mb = 0; mb < 4; mb++) {
#pragma unroll
    for (int i = 0; i < 4; i++) {
      int m = mb * 16 + quad * 4 + i;
      if (m < valid) {
        int tok = ltok[row0 + m];
        float w = lw[row0 + m];
#pragma unroll
        for (int nb = 0; nb < 4; nb++) {
          float v = acc[mb][nb][i] + bia[nb];
          atomicAdd(out + (size_t)tok * DIM + ncol + nb * 16, w * v);
        }
      }
    }
  }
}

extern "C" void kernel_launch(void* const* d_in, const int* in_sizes, int n_in,
                              void* d_out, int out_size, void* d_ws, size_t ws_size,
                              hipStream_t stream) {
  const float* x = (const float*)d_in[0];
  const float* Wg = (const float*)d_in[1];
  const float* W1 = (const float*)d_in[2];
  const float* b1 = (const float*)d_in[3];
  const float* lng = (const float*)d_in[4];
  const float* lnb = (const float*)d_in[5];
  const float* W2 = (const float*)d_in[6];
  const float* b2 = (const float*)d_in[7];
  float* out = (float*)d_out;

  char* ws = (char*)d_ws;
  int* counts = (int*)(ws + OFF_CNT);
  int* ltok = (int*)(ws + OFF_LTOK);
  float* lw = (float*)(ws + OFF_LW);
  float* s1 = (float*)(ws + OFF_S1);
  float* s2 = (float*)(ws + OFF_S2);
  ushort_t* xbf = (ushort_t*)(ws + OFF_XBF);
  ushort_t* hbuf = (ushort_t*)(ws + OFF_H);
  ushort_t* W1t = (ushort_t*)(ws + OFF_W1T);
  ushort_t* W2t = (ushort_t*)(ws + OFF_W2T);

  wconv_k<<<dim3(512, NEXP), 256, 0, stream>>>(W1, W2, W1t, W2t, counts);
  router_k<<<64, 256, 0, stream>>>(x, Wg, xbf, counts, ltok, lw, s1, s2, out);
  ffn1_k<<<dim3(MTILES, HID / 256), 256, 0, stream>>>(W1t, b1, counts, ltok, xbf, hbuf, s1, s2);
  ffn2_k<<<dim3(MTILES, DIM / 256, 2), 256, 0, stream>>>(W2t, b2, lng, lnb, counts, ltok,
                                                         lw, hbuf, s1, s2, out);
}

// Round 2
// 288.689 us; speedup vs baseline: 1.0004x; 1.0004x over previous
//
#include <hip/hip_runtime.h>
#include <hip/hip_bf16.h>

#define TOKENS 2048
#define DIM 512
#define NEXP 16
#define HID 2048
#define CAP 320                 /* rows per expert (mean 256, +4 sigma margin) */
#define NTPE (CAP / 64)         /* 5 m-tiles per expert */
#define MTILES (NEXP * NTPE)    /* 80 */
#define NROWS (NEXP * CAP)      /* 5120 */

typedef unsigned short ushort_t;
typedef __attribute__((ext_vector_type(8))) __bf16 bf16x8;
typedef __attribute__((ext_vector_type(4))) float f32x4;

// workspace byte offsets (total 90,260,480 <= known-good 90.3MB)
#define OFF_CNT 0
#define OFF_LTOK 1024
#define OFF_LW 21504
#define OFF_S1 41984
#define OFF_S2 62464
#define OFF_XBF 82944        /* 2048*512*2 = 2,097,152 -> ends 2,180,096 */
#define OFF_H 2180096        /* 5120*2048*2 = 20,971,520 -> ends 23,151,616 */
#define OFF_W1T 23151616     /* 33,554,432 -> ends 56,706,048 */
#define OFF_W2T 56706048     /* 33,554,432 -> ends 90,260,480 */

__device__ __forceinline__ ushort_t f2b(float f) {
  __bf16 b = (__bf16)f;
  return __builtin_bit_cast(unsigned short, b);
}
__device__ __forceinline__ float b2f(ushort_t u) {
  return __builtin_bit_cast(float, (unsigned)u << 16);
}

// ---------- weight convert+transpose (both W1 and W2 in one launch) ---------
// src[E][K][N] f32 -> dst[E][N][K] bf16
// 8 independent 32x32 sub-tiles per block; all 8 loads issued upfront
// (128B ILP/thread), ONE barrier, 8 independent transposed stores.
__global__ __launch_bounds__(256) void wconv_k(
    const float* __restrict__ W1, const float* __restrict__ W2,
    ushort_t* __restrict__ W1t, ushort_t* __restrict__ W2t,
    int* __restrict__ counts) {
  if (blockIdx.x == 0 && blockIdx.y == 0 && threadIdx.x < NEXP)
    counts[threadIdx.x] = 0;
  int bx = blockIdx.x;
  const float* src;
  ushort_t* dst;
  int K, N, nnc;
  if (bx < 128) { src = W1; dst = W1t; K = DIM; N = HID; nnc = 8; }
  else { src = W2; dst = W2t; K = HID; N = DIM; nnc = 2; bx -= 128; }
  int e = blockIdx.y;
  int kt = bx / nnc, nb = bx % nnc;
  int k0 = kt * 32, n0 = nb * 256;   /* block covers 32k x 256n */
  __shared__ ushort_t Ls[8][32 * 33];
  int t = threadIdx.x;
  int r = t >> 3, c4 = (t & 7) * 4;
  const float* sp = src + ((size_t)e * K + k0 + r) * N + n0 + c4;
  ushort_t* dp = dst + ((size_t)e * N + n0 + r) * K + k0 + c4;

  // 8 independent loads, all in flight together
  float4 v[8];
#pragma unroll
  for (int j = 0; j < 8; j++) v[j] = *(const float4*)(sp + j * 32);

#pragma unroll
  for (int j = 0; j < 8; j++) {
    Ls[j][r * 33 + c4 + 0] = f2b(v[j].x);
    Ls[j][r * 33 + c4 + 1] = f2b(v[j].y);
    Ls[j][r * 33 + c4 + 2] = f2b(v[j].z);
    Ls[j][r * 33 + c4 + 3] = f2b(v[j].w);
  }
  __syncthreads();
#pragma unroll
  for (int j = 0; j < 8; j++) {
    union { ushort_t u[4]; unsigned long long q; } o;
#pragma unroll
    for (int i = 0; i < 4; i++) o.u[i] = Ls[j][(c4 + i) * 33 + r];
    *(unsigned long long*)(dp + (size_t)(j * 32) * K) = o.q;
  }
}

// ---------------- router: logits, top-2, softmax, slot assignment -----------
__global__ __launch_bounds__(256) void router_k(
    const float* __restrict__ x, const float* __restrict__ Wg,
    ushort_t* __restrict__ xbf, int* __restrict__ counts,
    int* __restrict__ ltok, float* __restrict__ lw,
    float* __restrict__ s1, float* __restrict__ s2, float* __restrict__ out) {
  int t = threadIdx.x;
  {
    float4 z = {0.f, 0.f, 0.f, 0.f};
    float4* o4 = (float4*)out + blockIdx.x * 4096 + t;
#pragma unroll
    for (int i = 0; i < 16; i++) o4[i * 256] = z;
  }
  {
    int idx = blockIdx.x * 256 + t;
    if (idx < NROWS) { s1[idx] = 0.f; s2[idx] = 0.f; }
  }

  __shared__ float xs[4][512];
  __shared__ float lg[4][16];
  __shared__ int lcnt[NEXP];
  __shared__ int ltoks[NEXP][64];
  __shared__ float lws[NEXP][64];
  __shared__ int base_s[NEXP];

  if (t < NEXP) lcnt[t] = 0;
  __syncthreads();

  int lane = t & 63, w = t >> 6;
  int dq = lane >> 2, e4 = lane & 3;
  const float* wgp = Wg + dq * NEXP + e4 * 4;

  for (int it = 0; it < 8; it++) {
    int tok = blockIdx.x * 32 + w * 8 + it;
    const float* xr = x + (size_t)tok * DIM + lane * 8;
    float4 xa = *(const float4*)xr;
    float4 xb = *(const float4*)(xr + 4);
    union { ushort_t u[8]; uint4 v; } pk;
    pk.u[0] = f2b(xa.x); pk.u[1] = f2b(xa.y); pk.u[2] = f2b(xa.z); pk.u[3] = f2b(xa.w);
    pk.u[4] = f2b(xb.x); pk.u[5] = f2b(xb.y); pk.u[6] = f2b(xb.z); pk.u[7] = f2b(xb.w);
    *(uint4*)(xbf + (size_t)tok * DIM + lane * 8) = pk.v;
    *(float4*)&xs[w][lane * 8] = xa;
    *(float4*)&xs[w][lane * 8 + 4] = xb;

    float4 a = {0.f, 0.f, 0.f, 0.f};
#pragma unroll
    for (int kk = 0; kk < 32; kk++) {
      float xv = xs[w][kk * 16 + dq];
      float4 g = *(const float4*)(wgp + kk * 16 * NEXP);
      a.x += xv * g.x; a.y += xv * g.y; a.z += xv * g.z; a.w += xv * g.w;
    }
#pragma unroll
    for (int off = 32; off >= 4; off >>= 1) {
      a.x += __shfl_down(a.x, off);
      a.y += __shfl_down(a.y, off);
      a.z += __shfl_down(a.z, off);
      a.w += __shfl_down(a.w, off);
    }
    if (lane < 4) *(float4*)&lg[w][lane * 4] = a;
    if (lane == 0) {
      int i0 = 0;
      float v0 = lg[w][0];
#pragma unroll
      for (int e = 1; e < NEXP; e++)
        if (lg[w][e] > v0) { v0 = lg[w][e]; i0 = e; }
      int i1 = -1;
      float v1 = -3.4e38f;
#pragma unroll
      for (int e = 0; e < NEXP; e++)
        if (e != i0 && lg[w][e] > v1) { v1 = lg[w][e]; i1 = e; }
      float ex = __expf(v1 - v0);
      float w0 = 1.f / (1.f + ex);
      int p0 = atomicAdd(&lcnt[i0], 1);
      ltoks[i0][p0] = tok;
      lws[i0][p0] = w0;
      int p1 = atomicAdd(&lcnt[i1], 1);
      ltoks[i1][p1] = tok;
      lws[i1][p1] = ex / (1.f + ex);
    }
  }
  __syncthreads();
  if (t < NEXP) base_s[t] = atomicAdd(&counts[t], lcnt[t]);
  __syncthreads();
  int e = t >> 4, i0 = t & 15;
  int n = lcnt[e], b = base_s[e];
  for (int i = i0; i < n; i += 16) {
    int slot = b + i;
    if (slot < CAP) {
      ltok[e * CAP + slot] = ltoks[e][i];
      lw[e * CAP + slot] = lws[e][i];
    }
  }
}

// ---------------- GEMM1: h = silu(x @ W1 + b1), store bf16 + row stats ------
// W1t: [E][H][D] bf16 (k=D contiguous). M=64, N=256/block.
// Double-buffered LDS, 1 barrier/K-step, loads pipelined 1-2 steps ahead.
__global__ __launch_bounds__(256) void ffn1_k(
    const ushort_t* __restrict__ W1t, const float* __restrict__ b1,
    const int* __restrict__ counts, const int* __restrict__ ltok,
    const ushort_t* __restrict__ xbf, ushort_t* __restrict__ hbuf,
    float* __restrict__ s1, float* __restrict__ s2) {
  int e = blockIdx.x / NTPE, mt = blockIdx.x % NTPE;
  int cnt = counts[e];
  if (cnt - mt * 64 <= 0) return;
  int row0 = e * CAP + mt * 64;
  int h0 = blockIdx.y * 256;

  __shared__ __align__(16) ushort_t As[2][64 * 40];

  int t = threadIdx.x;
  int lane = t & 63, wave = t >> 6;
  int quad = lane >> 4, l16 = lane & 15;

  int sr = t >> 2, sp = t & 3;
  int stok = ltok[row0 + sr];
  bool sok = (unsigned)stok < TOKENS;
  const ushort_t* sx = xbf + (size_t)(sok ? stok : 0) * DIM + sp * 8;

  int ncol = h0 + wave * 64 + l16;
  const ushort_t* bb = W1t + ((size_t)e * HID + ncol) * DIM + quad * 8;

  f32x4 acc[4][4];
#pragma unroll
  for (int a = 0; a < 4; a++)
#pragma unroll
    for (int b = 0; b < 4; b++) acc[a][b] = {0.f, 0.f, 0.f, 0.f};

  // prologue: A(0) -> LDS[0], A(1) in regs, B(0) in regs
  uint4 avB = {0u, 0u, 0u, 0u};
  {
    uint4 avA = {0u, 0u, 0u, 0u};
    if (sok) {
      avA = *(const uint4*)(sx);
      avB = *(const uint4*)(sx + 32);
    }
    *(uint4*)(&As[0][sr * 40 + sp * 8]) = avA;
  }
  bf16x8 bc[4];
#pragma unroll
  for (int nb = 0; nb < 4; nb++)
    bc[nb] = *(const bf16x8*)(bb + (size_t)nb * 16 * DIM);

#pragma unroll
  for (int ks = 0; ks < 16; ks++) {
    __syncthreads();  // LDS[ks&1] ready
    // issue next loads right after the barrier: full-iteration cover
    bf16x8 bn[4];
    if (ks < 15) {
#pragma unroll
      for (int nb = 0; nb < 4; nb++)
        bn[nb] = *(const bf16x8*)(bb + (size_t)nb * 16 * DIM + (ks + 1) * 32);
    }
    uint4 avN = {0u, 0u, 0u, 0u};
    if (ks < 14 && sok) avN = *(const uint4*)(sx + (ks + 2) * 32);

    bf16x8 af[4];
#pragma unroll
    for (int mb = 0; mb < 4; mb++)
      af[mb] = *(const bf16x8*)(&As[ks & 1][(mb * 16 + l16) * 40 + quad * 8]);
#pragma unroll
    for (int mb = 0; mb < 4; mb++)
#pragma unroll
      for (int nb = 0; nb < 4; nb++)
        acc[mb][nb] = __builtin_amdgcn_mfma_f32_16x16x32_bf16(af[mb], bc[nb], acc[mb][nb], 0, 0, 0);

    if (ks < 15) {
      *(uint4*)(&As[(ks + 1) & 1][sr * 40 + sp * 8]) = avB;
      avB = avN;
#pragma unroll
      for (int nb = 0; nb < 4; nb++) bc[nb] = bn[nb];
    }
  }

  float bia[4];
#pragma unroll
  for (int nb = 0; nb < 4; nb++) bia[nb] = b1[e * HID + ncol + nb * 16];
#pragma unroll
  for (int mb = 0; mb < 4; mb++) {
#pragma unroll
    for (int i = 0; i < 4; i++) {
      int m = mb * 16 + quad * 4 + i;
      size_t rowg = (size_t)(row0 + m);
      float ps = 0.f, qs = 0.f;
#pragma unroll
      for (int nb = 0; nb < 4; nb++) {
        float v = acc[mb][nb][i] + bia[nb];
        v = v / (1.f + __expf(-v));
        hbuf[rowg * HID + ncol + nb * 16] = f2b(v);
        ps += v;
        qs += v * v;
      }
      ps += __shfl_down(ps, 8); qs += __shfl_down(qs, 8);
      ps += __shfl_down(ps, 4); qs += __shfl_down(qs, 4);
      ps += __shfl_down(ps, 2); qs += __shfl_down(qs, 2);
      ps += __shfl_down(ps, 1); qs += __shfl_down(qs, 1);
      if (l16 == 0) {
        atomicAdd(&s1[rowg], ps);
        atomicAdd(&s2[rowg], qs);
      }
    }
  }
}

// ---------------- GEMM2: out[t] += w * (LN(h) @ W2 + b2) --------------------
// W2t: [E][D][H] bf16 (k=H contiguous). M=64, N=256/block, K split in 2 (z).
// gamma/beta pre-staged in LDS; double-buffered pipelined K-loop.
__global__ __launch_bounds__(256) void ffn2_k(
    const ushort_t* __restrict__ W2t, const float* __restrict__ b2,
    const float* __restrict__ lng, const float* __restrict__ lnb,
    const int* __restrict__ counts, const int* __restrict__ ltok,
    const float* __restrict__ lw, const ushort_t* __restrict__ hbuf,
    const float* __restrict__ s1, const float* __restrict__ s2,
    float* __restrict__ out) {
  int e = blockIdx.x / NTPE, mt = blockIdx.x % NTPE;
  int cnt = counts[e];
  int valid = cnt - mt * 64;
  if (valid <= 0) return;
  valid = valid > 64 ? 64 : valid;
  int row0 = e * CAP + mt * 64;
  int n0 = blockIdx.y * 256;
  int kbeg = blockIdx.z * (HID / 2);

  __shared__ __align__(16) ushort_t As[2][64 * 40];
  __shared__ float Gs[1024];
  __shared__ float Cs[1024];

  int t = threadIdx.x;
  int lane = t & 63, wave = t >> 6;
  int quad = lane >> 4, l16 = lane & 15;

  // stage gamma/beta slice once
  *(float4*)&Gs[t * 4] = *(const float4*)(lng + (size_t)e * HID + kbeg + t * 4);
  *(float4*)&Cs[t * 4] = *(const float4*)(lnb + (size_t)e * HID + kbeg + t * 4);

  int sr = t >> 2, sp = t & 3;
  size_t srow = (size_t)(row0 + sr);
  const ushort_t* hr = hbuf + srow * HID + kbeg + sp * 8;
  float smu = s1[srow] * (1.f / HID);
  float var = s2[srow] * (1.f / HID) - smu * smu;
  float srs = rsqrtf(var + 1e-5f);

  int ncol = n0 + wave * 64 + l16;
  const ushort_t* bb = W2t + ((size_t)e * DIM + ncol) * HID + kbeg + quad * 8;

  f32x4 acc[4][4];
#pragma unroll
  for (int a = 0; a < 4; a++)
#pragma unroll
    for (int b = 0; b < 4; b++) acc[a][b] = {0.f, 0.f, 0.f, 0.f};

  uint4 hvA = *(const uint4*)(hr);
  uint4 hvB = *(const uint4*)(hr + 32);
  __syncthreads();  // Gs/Cs ready

  // process step0 -> LDS[0]
  {
    union { uint4 v; ushort_t u[8]; } hv;
    hv.v = hvA;
    int sb = sp * 8;
    union { ushort_t u[8]; uint4 v; } pk;
#pragma unroll
    for (int j = 0; j < 8; j++) {
      float f = (b2f(hv.u[j]) - smu) * srs;
      pk.u[j] = f2b(f * Gs[sb + j] + Cs[sb + j]);
    }
    *(uint4*)(&As[0][sr * 40 + sp * 8]) = pk.v;
  }
  bf16x8 bc[4];
#pragma unroll
  for (int nb = 0; nb < 4; nb++)
    bc[nb] = *(const bf16x8*)(bb + (size_t)nb * 16 * HID);

#pragma unroll 8
  for (int ks = 0; ks < 32; ks++) {
    __syncthreads();  // LDS[ks&1] ready
    bf16x8 bn[4];
    if (ks < 31) {
#pragma unroll
      for (int nb = 0; nb < 4; nb++)
        bn[nb] = *(const bf16x8*)(bb + (size_t)nb * 16 * HID + (ks + 1) * 32);
    }
    uint4 hvN = {0u, 0u, 0u, 0u};
    if (ks < 30) hvN = *(const uint4*)(hr + (ks + 2) * 32);

    bf16x8 af[4];
#pragma unroll
    for (int mb = 0; mb < 4; mb++)
      af[mb] = *(const bf16x8*)(&As[ks & 1][(mb * 16 + l16) * 40 + quad * 8]);
#pragma unroll
    for (int mb = 0; mb < 4; mb++)
#pragma unroll
      for (int nb = 0; nb < 4; nb++)
        acc[mb][nb] = __builtin_amdgcn_mfma_f32_16x16x32_bf16(af[mb], bc[nb], acc[mb][nb], 0, 0, 0);

    if (ks < 31) {
      union { uint4 v; ushort_t u[8]; } hv;
      hv.v = hvB;
      int sb = (ks + 1) * 32 + sp * 8;
      union { ushort_t u[8]; uint4 v; } pk;
#pragma unroll
      for (int j = 0; j < 8; j++) {
        float f = (b2f(hv.u[j]) - smu) * srs;
        pk.u[j] = f2b(f * Gs[sb + j] + Cs[sb + j]);
      }
      *(uint4*)(&As[(ks + 1) & 1][sr * 40 + sp * 8]) = pk.v;
      hvB = hvN;
#pragma unroll
      for (int nb = 0; nb < 4; nb++) bc[nb] = bn[nb];
    }
  }

  bool addb = (blockIdx.z == 0);
  float bia[4];
#pragma unroll
  for (int nb = 0; nb < 4; nb++)
    bia[nb] = addb ? b2[e * DIM + ncol + nb * 16] : 0.f;
#pragma unroll
  for (int mb = 0; mb < 4; mb++) {
#pragma unroll
    for (int i = 0; i < 4; i++) {
      int m = mb * 16 + quad * 4 + i;
      if (m < valid) {
        int tok = ltok[row0 + m];
        float w = lw[row0 + m];
#pragma unroll
        for (int nb = 0; nb < 4; nb++) {
          float v = acc[mb][nb][i] + bia[nb];
          atomicAdd(out + (size_t)tok * DIM + ncol + nb * 16, w * v);
        }
      }
    }
  }
}

extern "C" void kernel_launch(void* const* d_in, const int* in_sizes, int n_in,
                              void* d_out, int out_size, void* d_ws, size_t ws_size,
                              hipStream_t stream) {
  const float* x = (const float*)d_in[0];
  const float* Wg = (const float*)d_in[1];
  const float* W1 = (const float*)d_in[2];
  const float* b1 = (const float*)d_in[3];
  const float* lng = (const float*)d_in[4];
  const float* lnb = (const float*)d_in[5];
  const float* W2 = (const float*)d_in[6];
  const float* b2 = (const float*)d_in[7];
  float* out = (float*)d_out;

  char* ws = (char*)d_ws;
  int* counts = (int*)(ws + OFF_CNT);
  int* ltok = (int*)(ws + OFF_LTOK);
  float* lw = (float*)(ws + OFF_LW);
  float* s1 = (float*)(ws + OFF_S1);
  float* s2 = (float*)(ws + OFF_S2);
  ushort_t* xbf = (ushort_t*)(ws + OFF_XBF);
  ushort_t* hbuf = (ushort_t*)(ws + OFF_H);
  ushort_t* W1t = (ushort_t*)(ws + OFF_W1T);
  ushort_t* W2t = (ushort_t*)(ws + OFF_W2T);

  wconv_k<<<dim3(256, NEXP), 256, 0, stream>>>(W1, W2, W1t, W2t, counts);
  router_k<<<64, 256, 0, stream>>>(x, Wg, xbf, counts, ltok, lw, s1, s2, out);
  ffn1_k<<<dim3(MTILES, HID / 256), 256, 0, stream>>>(W1t, b1, counts, ltok, xbf, hbuf, s1, s2);
  ffn2_k<<<dim3(MTILES, DIM / 256, 2), 256, 0, stream>>>(W2t, b2, lng, lnb, counts, ltok,
                                                         lw, hbuf, s1, s2, out);
}

// Round 3
// 269.627 us; speedup vs baseline: 1.0711x; 1.0707x over previous
//
#include <hip/hip_runtime.h>
#include <hip/hip_bf16.h>

#define TOKENS 2048
#define DIM 512
#define NEXP 16
#define HID 2048
#define CAP 320                 /* rows per expert (mean 256, +4 sigma margin) */
#define NTPE (CAP / 64)         /* 5 m-tiles per expert */
#define MTILES (NEXP * NTPE)    /* 80 */
#define NROWS (NEXP * CAP)      /* 5120 */

typedef unsigned short ushort_t;
typedef __attribute__((ext_vector_type(8))) __bf16 bf16x8;
typedef __attribute__((ext_vector_type(4))) float f32x4;

// workspace byte offsets (total 90,260,480 <= known-good 90.3MB)
#define OFF_CNT 0
#define OFF_LTOK 1024
#define OFF_LW 21504
#define OFF_S1 41984
#define OFF_S2 62464
#define OFF_XBF 82944        /* 2048*512*2 = 2,097,152 -> ends 2,180,096 */
#define OFF_H 2180096        /* 5120*2048*2 = 20,971,520 -> ends 23,151,616 */
#define OFF_W1T 23151616     /* 33,554,432 -> ends 56,706,048 */
#define OFF_W2T 56706048     /* 33,554,432 -> ends 90,260,480 */

__device__ __forceinline__ ushort_t f2b(float f) {
  __bf16 b = (__bf16)f;
  return __builtin_bit_cast(unsigned short, b);
}
__device__ __forceinline__ float b2f(ushort_t u) {
  return __builtin_bit_cast(float, (unsigned)u << 16);
}

// ---------- weight convert+transpose (both W1 and W2 in one launch) ---------
// src[E][K][N] f32 -> dst tiled [E][N/16][K/32][512] bf16, where tile element
// o = n_local*32 + k_local  (exactly the MFMA B-fragment order the ffn
// kernels read: offset l16*32 + quad*8).
// Block covers a 32k x 256n region: loads are 1KB/row contiguous, stores are
// 16 x 1KB tiles, each written as 4 x 256B contiguous runs by ONE wave
// (no cross-XCD partial-line sharing).
__global__ __launch_bounds__(256) void wconv_k(
    const float* __restrict__ W1, const float* __restrict__ W2,
    ushort_t* __restrict__ W1t, ushort_t* __restrict__ W2t,
    int* __restrict__ counts) {
  if (blockIdx.x == 0 && blockIdx.y == 0 && threadIdx.x < NEXP)
    counts[threadIdx.x] = 0;
  int bx = blockIdx.x;
  const float* src;
  ushort_t* dst;
  int K, N, nnc;
  if (bx < 128) { src = W1; dst = W1t; K = DIM; N = HID; nnc = 8; }
  else { src = W2; dst = W2t; K = HID; N = DIM; nnc = 2; bx -= 128; }
  int e = blockIdx.y;
  int kt = bx / nnc, nb = bx % nnc;
  int k0 = kt * 32, n0 = nb * 256;
  __shared__ ushort_t Ls[32 * 264];   /* [32 k][256 n] pad 8 -> 16,896B */
  int t = threadIdx.x;
  int r = t >> 3, c4 = (t & 7) * 4;
  const float* sp = src + ((size_t)e * K + k0 + r) * N + n0 + c4;

  float4 v[8];
#pragma unroll
  for (int j = 0; j < 8; j++) v[j] = *(const float4*)(sp + j * 32);
#pragma unroll
  for (int j = 0; j < 8; j++) {
    union { ushort_t u[4]; uint2 d; } p;
    p.u[0] = f2b(v[j].x); p.u[1] = f2b(v[j].y);
    p.u[2] = f2b(v[j].z); p.u[3] = f2b(v[j].w);
    *(uint2*)&Ls[r * 264 + c4 + j * 32] = p.d;
  }
  __syncthreads();

  // store: 16 threads per 1KB tile; instr i writes 256B contiguous across
  // lanes (l16). tile_n = t>>4 (16 tiles per block).
  int tile_n = t >> 4;
  int l16 = t & 15;
  size_t tbase =
      ((size_t)(e * (N >> 4) + (n0 >> 4) + tile_n) * (K >> 5) + kt) * 512;
#pragma unroll
  for (int i = 0; i < 4; i++) {
    int o = i * 128 + l16 * 8;      /* element offset within 512-elem tile */
    int nl = o >> 5, kk = o & 31;   /* n_local, k start (kk in {0,8,16,24}) */
    int col = tile_n * 16 + nl;
    union { ushort_t u[8]; uint4 q; } s;
#pragma unroll
    for (int j = 0; j < 8; j++) s.u[j] = Ls[(kk + j) * 264 + col];
    *(uint4*)(dst + tbase + o) = s.q;
  }
}

// ---------------- router: logits, top-2, softmax, slot assignment -----------
__global__ __launch_bounds__(256) void router_k(
    const float* __restrict__ x, const float* __restrict__ Wg,
    ushort_t* __restrict__ xbf, int* __restrict__ counts,
    int* __restrict__ ltok, float* __restrict__ lw,
    float* __restrict__ s1, float* __restrict__ s2, float* __restrict__ out) {
  int t = threadIdx.x;
  {
    float4 z = {0.f, 0.f, 0.f, 0.f};
    float4* o4 = (float4*)out + blockIdx.x * 4096 + t;
#pragma unroll
    for (int i = 0; i < 16; i++) o4[i * 256] = z;
  }
  {
    int idx = blockIdx.x * 256 + t;
    if (idx < NROWS) { s1[idx] = 0.f; s2[idx] = 0.f; }
  }

  __shared__ float xs[4][512];
  __shared__ float lg[4][16];
  __shared__ int lcnt[NEXP];
  __shared__ int ltoks[NEXP][64];
  __shared__ float lws[NEXP][64];
  __shared__ int base_s[NEXP];

  if (t < NEXP) lcnt[t] = 0;
  __syncthreads();

  int lane = t & 63, w = t >> 6;
  int dq = lane >> 2, e4 = lane & 3;
  const float* wgp = Wg + dq * NEXP + e4 * 4;

  for (int it = 0; it < 8; it++) {
    int tok = blockIdx.x * 32 + w * 8 + it;
    const float* xr = x + (size_t)tok * DIM + lane * 8;
    float4 xa = *(const float4*)xr;
    float4 xb = *(const float4*)(xr + 4);
    union { ushort_t u[8]; uint4 v; } pk;
    pk.u[0] = f2b(xa.x); pk.u[1] = f2b(xa.y); pk.u[2] = f2b(xa.z); pk.u[3] = f2b(xa.w);
    pk.u[4] = f2b(xb.x); pk.u[5] = f2b(xb.y); pk.u[6] = f2b(xb.z); pk.u[7] = f2b(xb.w);
    *(uint4*)(xbf + (size_t)tok * DIM + lane * 8) = pk.v;
    *(float4*)&xs[w][lane * 8] = xa;
    *(float4*)&xs[w][lane * 8 + 4] = xb;

    float4 a = {0.f, 0.f, 0.f, 0.f};
#pragma unroll
    for (int kk = 0; kk < 32; kk++) {
      float xv = xs[w][kk * 16 + dq];
      float4 g = *(const float4*)(wgp + kk * 16 * NEXP);
      a.x += xv * g.x; a.y += xv * g.y; a.z += xv * g.z; a.w += xv * g.w;
    }
#pragma unroll
    for (int off = 32; off >= 4; off >>= 1) {
      a.x += __shfl_down(a.x, off);
      a.y += __shfl_down(a.y, off);
      a.z += __shfl_down(a.z, off);
      a.w += __shfl_down(a.w, off);
    }
    if (lane < 4) *(float4*)&lg[w][lane * 4] = a;
    if (lane == 0) {
      int i0 = 0;
      float v0 = lg[w][0];
#pragma unroll
      for (int e = 1; e < NEXP; e++)
        if (lg[w][e] > v0) { v0 = lg[w][e]; i0 = e; }
      int i1 = -1;
      float v1 = -3.4e38f;
#pragma unroll
      for (int e = 0; e < NEXP; e++)
        if (e != i0 && lg[w][e] > v1) { v1 = lg[w][e]; i1 = e; }
      float ex = __expf(v1 - v0);
      float w0 = 1.f / (1.f + ex);
      int p0 = atomicAdd(&lcnt[i0], 1);
      ltoks[i0][p0] = tok;
      lws[i0][p0] = w0;
      int p1 = atomicAdd(&lcnt[i1], 1);
      ltoks[i1][p1] = tok;
      lws[i1][p1] = ex / (1.f + ex);
    }
  }
  __syncthreads();
  if (t < NEXP) base_s[t] = atomicAdd(&counts[t], lcnt[t]);
  __syncthreads();
  int e = t >> 4, i0 = t & 15;
  int n = lcnt[e], b = base_s[e];
  for (int i = i0; i < n; i += 16) {
    int slot = b + i;
    if (slot < CAP) {
      ltok[e * CAP + slot] = ltoks[e][i];
      lw[e * CAP + slot] = lws[e][i];
    }
  }
}

// ---------------- GEMM1: h = silu(x @ W1 + b1), store bf16 + row stats ------
// W1t tiled: [E][HID/16][DIM/32][512], tile elem = n_local*32 + k_local.
// Fragment (wave,nb,ks) = base + nb*8192 + ks*512 + l16*32 + quad*8 —
// a wave's fragment read covers a contiguous 1KB tile.
__global__ __launch_bounds__(256) void ffn1_k(
    const ushort_t* __restrict__ W1t, const float* __restrict__ b1,
    const int* __restrict__ counts, const int* __restrict__ ltok,
    const ushort_t* __restrict__ xbf, ushort_t* __restrict__ hbuf,
    float* __restrict__ s1, float* __restrict__ s2) {
  int e = blockIdx.x / NTPE, mt = blockIdx.x % NTPE;
  int cnt = counts[e];
  if (cnt - mt * 64 <= 0) return;
  int row0 = e * CAP + mt * 64;
  int h0 = blockIdx.y * 256;

  __shared__ __align__(16) ushort_t As[2][64 * 40];

  int t = threadIdx.x;
  int lane = t & 63, wave = t >> 6;
  int quad = lane >> 4, l16 = lane & 15;

  int sr = t >> 2, sp = t & 3;
  int stok = ltok[row0 + sr];
  bool sok = (unsigned)stok < TOKENS;
  const ushort_t* sx = xbf + (size_t)(sok ? stok : 0) * DIM + sp * 8;

  int ncol = h0 + wave * 64 + l16;
  const ushort_t* bb = W1t +
      ((size_t)(e * 128 + (h0 >> 4) + wave * 4) * 16) * 512 + l16 * 32 + quad * 8;

  f32x4 acc[4][4];
#pragma unroll
  for (int a = 0; a < 4; a++)
#pragma unroll
    for (int b = 0; b < 4; b++) acc[a][b] = {0.f, 0.f, 0.f, 0.f};

  // prologue: A(0) -> LDS[0], A(1) in regs, B(0) in regs
  uint4 avB = {0u, 0u, 0u, 0u};
  {
    uint4 avA = {0u, 0u, 0u, 0u};
    if (sok) {
      avA = *(const uint4*)(sx);
      avB = *(const uint4*)(sx + 32);
    }
    *(uint4*)(&As[0][sr * 40 + sp * 8]) = avA;
  }
  bf16x8 bc[4];
#pragma unroll
  for (int nb = 0; nb < 4; nb++)
    bc[nb] = *(const bf16x8*)(bb + nb * 8192);

#pragma unroll
  for (int ks = 0; ks < 16; ks++) {
    __syncthreads();  // LDS[ks&1] ready
    bf16x8 bn[4];
    if (ks < 15) {
#pragma unroll
      for (int nb = 0; nb < 4; nb++)
        bn[nb] = *(const bf16x8*)(bb + nb * 8192 + (ks + 1) * 512);
    }
    uint4 avN = {0u, 0u, 0u, 0u};
    if (ks < 14 && sok) avN = *(const uint4*)(sx + (ks + 2) * 32);

    bf16x8 af[4];
#pragma unroll
    for (int mb = 0; mb < 4; mb++)
      af[mb] = *(const bf16x8*)(&As[ks & 1][(mb * 16 + l16) * 40 + quad * 8]);
#pragma unroll
    for (int mb = 0; mb < 4; mb++)
#pragma unroll
      for (int nb = 0; nb < 4; nb++)
        acc[mb][nb] = __builtin_amdgcn_mfma_f32_16x16x32_bf16(af[mb], bc[nb], acc[mb][nb], 0, 0, 0);

    if (ks < 15) {
      *(uint4*)(&As[(ks + 1) & 1][sr * 40 + sp * 8]) = avB;
      avB = avN;
#pragma unroll
      for (int nb = 0; nb < 4; nb++) bc[nb] = bn[nb];
    }
  }

  float bia[4];
#pragma unroll
  for (int nb = 0; nb < 4; nb++) bia[nb] = b1[e * HID + ncol + nb * 16];
#pragma unroll
  for (int mb = 0; mb < 4; mb++) {
#pragma unroll
    for (int i = 0; i < 4; i++) {
      int m = mb * 16 + quad * 4 + i;
      size_t rowg = (size_t)(row0 + m);
      float ps = 0.f, qs = 0.f;
#pragma unroll
      for (int nb = 0; nb < 4; nb++) {
        float v = acc[mb][nb][i] + bia[nb];
        v = v / (1.f + __expf(-v));
        hbuf[rowg * HID + ncol + nb * 16] = f2b(v);
        ps += v;
        qs += v * v;
      }
      ps += __shfl_down(ps, 8); qs += __shfl_down(qs, 8);
      ps += __shfl_down(ps, 4); qs += __shfl_down(qs, 4);
      ps += __shfl_down(ps, 2); qs += __shfl_down(qs, 2);
      ps += __shfl_down(ps, 1); qs += __shfl_down(qs, 1);
      if (l16 == 0) {
        atomicAdd(&s1[rowg], ps);
        atomicAdd(&s2[rowg], qs);
      }
    }
  }
}

// ---------------- GEMM2: out[t] += w * (LN(h) @ W2 + b2) --------------------
// W2t tiled: [E][DIM/16][HID/32][512]. K split in 2 via blockIdx.z.
__global__ __launch_bounds__(256) void ffn2_k(
    const ushort_t* __restrict__ W2t, const float* __restrict__ b2,
    const float* __restrict__ lng, const float* __restrict__ lnb,
    const int* __restrict__ counts, const int* __restrict__ ltok,
    const float* __restrict__ lw, const ushort_t* __restrict__ hbuf,
    const float* __restrict__ s1, const float* __restrict__ s2,
    float* __restrict__ out) {
  int e = blockIdx.x / NTPE, mt = blockIdx.x % NTPE;
  int cnt = counts[e];
  int valid = cnt - mt * 64;
  if (valid <= 0) return;
  valid = valid > 64 ? 64 : valid;
  int row0 = e * CAP + mt * 64;
  int n0 = blockIdx.y * 256;
  int kbeg = blockIdx.z * (HID / 2);

  __shared__ __align__(16) ushort_t As[2][64 * 40];
  __shared__ float Gs[1024];
  __shared__ float Cs[1024];

  int t = threadIdx.x;
  int lane = t & 63, wave = t >> 6;
  int quad = lane >> 4, l16 = lane & 15;

  // stage gamma/beta slice once
  *(float4*)&Gs[t * 4] = *(const float4*)(lng + (size_t)e * HID + kbeg + t * 4);
  *(float4*)&Cs[t * 4] = *(const float4*)(lnb + (size_t)e * HID + kbeg + t * 4);

  int sr = t >> 2, sp = t & 3;
  size_t srow = (size_t)(row0 + sr);
  const ushort_t* hr = hbuf + srow * HID + kbeg + sp * 8;
  float smu = s1[srow] * (1.f / HID);
  float var = s2[srow] * (1.f / HID) - smu * smu;
  float srs = rsqrtf(var + 1e-5f);

  int ncol = n0 + wave * 64 + l16;
  const ushort_t* bb = W2t +
      ((size_t)(e * 32 + (n0 >> 4) + wave * 4) * 64 + blockIdx.z * 32) * 512 +
      l16 * 32 + quad * 8;

  f32x4 acc[4][4];
#pragma unroll
  for (int a = 0; a < 4; a++)
#pragma unroll
    for (int b = 0; b < 4; b++) acc[a][b] = {0.f, 0.f, 0.f, 0.f};

  uint4 hvA = *(const uint4*)(hr);
  uint4 hvB = *(const uint4*)(hr + 32);
  __syncthreads();  // Gs/Cs ready

  // process step0 -> LDS[0]
  {
    union { uint4 v; ushort_t u[8]; } hv;
    hv.v = hvA;
    int sb = sp * 8;
    union { ushort_t u[8]; uint4 v; } pk;
#pragma unroll
    for (int j = 0; j < 8; j++) {
      float f = (b2f(hv.u[j]) - smu) * srs;
      pk.u[j] = f2b(f * Gs[sb + j] + Cs[sb + j]);
    }
    *(uint4*)(&As[0][sr * 40 + sp * 8]) = pk.v;
  }
  bf16x8 bc[4];
#pragma unroll
  for (int nb = 0; nb < 4; nb++)
    bc[nb] = *(const bf16x8*)(bb + nb * 32768);

#pragma unroll 8
  for (int ks = 0; ks < 32; ks++) {
    __syncthreads();  // LDS[ks&1] ready
    bf16x8 bn[4];
    if (ks < 31) {
#pragma unroll
      for (int nb = 0; nb < 4; nb++)
        bn[nb] = *(const bf16x8*)(bb + nb * 32768 + (ks + 1) * 512);
    }
    uint4 hvN = {0u, 0u, 0u, 0u};
    if (ks < 30) hvN = *(const uint4*)(hr + (ks + 2) * 32);

    bf16x8 af[4];
#pragma unroll
    for (int mb = 0; mb < 4; mb++)
      af[mb] = *(const bf16x8*)(&As[ks & 1][(mb * 16 + l16) * 40 + quad * 8]);
#pragma unroll
    for (int mb = 0; mb < 4; mb++)
#pragma unroll
      for (int nb = 0; nb < 4; nb++)
        acc[mb][nb] = __builtin_amdgcn_mfma_f32_16x16x32_bf16(af[mb], bc[nb], acc[mb][nb], 0, 0, 0);

    if (ks < 31) {
      union { uint4 v; ushort_t u[8]; } hv;
      hv.v = hvB;
      int sb = (ks + 1) * 32 + sp * 8;
      union { ushort_t u[8]; uint4 v; } pk;
#pragma unroll
      for (int j = 0; j < 8; j++) {
        float f = (b2f(hv.u[j]) - smu) * srs;
        pk.u[j] = f2b(f * Gs[sb + j] + Cs[sb + j]);
      }
      *(uint4*)(&As[(ks + 1) & 1][sr * 40 + sp * 8]) = pk.v;
      hvB = hvN;
#pragma unroll
      for (int nb = 0; nb < 4; nb++) bc[nb] = bn[nb];
    }
  }

  bool addb = (blockIdx.z == 0);
  float bia[4];
#pragma unroll
  for (int nb = 0; nb < 4; nb++)
    bia[nb] = addb ? b2[e * DIM + ncol + nb * 16] : 0.f;
#pragma unroll
  for (int mb = 0; mb < 4; mb++) {
#pragma unroll
    for (int i = 0; i < 4; i++) {
      int m = mb * 16 + quad * 4 + i;
      if (m < valid) {
        int tok = ltok[row0 + m];
        float w = lw[row0 + m];
#pragma unroll
        for (int nb = 0; nb < 4; nb++) {
          float v = acc[mb][nb][i] + bia[nb];
          atomicAdd(out + (size_t)tok * DIM + ncol + nb * 16, w * v);
        }
      }
    }
  }
}

extern "C" void kernel_launch(void* const* d_in, const int* in_sizes, int n_in,
                              void* d_out, int out_size, void* d_ws, size_t ws_size,
                              hipStream_t stream) {
  const float* x = (const float*)d_in[0];
  const float* Wg = (const float*)d_in[1];
  const float* W1 = (const float*)d_in[2];
  const float* b1 = (const float*)d_in[3];
  const float* lng = (const float*)d_in[4];
  const float* lnb = (const float*)d_in[5];
  const float* W2 = (const float*)d_in[6];
  const float* b2 = (const float*)d_in[7];
  float* out = (float*)d_out;

  char* ws = (char*)d_ws;
  int* counts = (int*)(ws + OFF_CNT);
  int* ltok = (int*)(ws + OFF_LTOK);
  float* lw = (float*)(ws + OFF_LW);
  float* s1 = (float*)(ws + OFF_S1);
  float* s2 = (float*)(ws + OFF_S2);
  ushort_t* xbf = (ushort_t*)(ws + OFF_XBF);
  ushort_t* hbuf = (ushort_t*)(ws + OFF_H);
  ushort_t* W1t = (ushort_t*)(ws + OFF_W1T);
  ushort_t* W2t = (ushort_t*)(ws + OFF_W2T);

  wconv_k<<<dim3(256, NEXP), 256, 0, stream>>>(W1, W2, W1t, W2t, counts);
  router_k<<<64, 256, 0, stream>>>(x, Wg, xbf, counts, ltok, lw, s1, s2, out);
  ffn1_k<<<dim3(MTILES, HID / 256), 256, 0, stream>>>(W1t, b1, counts, ltok, xbf, hbuf, s1, s2);
  ffn2_k<<<dim3(MTILES, DIM / 256, 2), 256, 0, stream>>>(W2t, b2, lng, lnb, counts, ltok,
                                                         lw, hbuf, s1, s2, out);
}